// Round 3
// baseline (409.772 us; speedup 1.0000x reference)
//
#include <hip/hip_runtime.h>
#include <hip/hip_bf16.h>

typedef __attribute__((ext_vector_type(8))) short s16x8;
typedef __attribute__((ext_vector_type(4))) float f32x4;
typedef __attribute__((ext_vector_type(4))) unsigned short us4;
typedef __attribute__((ext_vector_type(4))) unsigned int u32x4;

#define MFMA16(a,b,c) __builtin_amdgcn_mfma_f32_16x16x32_bf16((a),(b),(c),0,0,0)

__device__ __forceinline__ float b2f(unsigned short u){
  union{unsigned u; float f;} v; v.u = ((unsigned)u)<<16; return v.f;
}
__device__ __forceinline__ unsigned short f2b(float f){
  union{float f; unsigned u;} v; v.f = f;
  unsigned r = v.u + 0x7fffu + ((v.u>>16)&1u);
  return (unsigned short)(r>>16);
}

__device__ __forceinline__ void gl_lds16(const void* gp, void* lp){
  __builtin_amdgcn_global_load_lds((const __attribute__((address_space(1))) void*)gp,
                                   (__attribute__((address_space(3))) void*)lp, 16, 0, 0);
}

// stage 64 rows x 256 cols bf16 (row stride `stride` elems) with XOR swizzle ((row&7)<<4)
__device__ __forceinline__ void stage_64x256(void* lds, const unsigned short* g, int stride){
  const int t = threadIdx.x, wv = t>>6;
  #pragma unroll
  for (int i=0;i<8;++i){
    int ch = i*256 + t;
    int row = ch>>5, cc = ch&31, sc = cc ^ (row&7);
    gl_lds16((const char*)(g + (size_t)row*stride) + sc*16,
             (char*)lds + (((size_t)i*256 + wv*64)<<4));
  }
}
// stage 256 rows x 64 cols bf16 (row stride 4096 elems) with XOR swizzle ((row&7)<<4)
__device__ __forceinline__ void stage_256x64(void* lds, const unsigned short* g){
  const int t = threadIdx.x, wv = t>>6;
  #pragma unroll
  for (int i=0;i<8;++i){
    int ch = i*256 + t;
    int row = ch>>3, cc = ch&7, sc = cc ^ (row&7);
    gl_lds16((const char*)(g + (size_t)row*4096) + sc*16,
             (char*)lds + (((size_t)i*256 + wv*64)<<4));
  }
}

// ---------------- f32 -> bf16 cast ----------------
__global__ void k_cvt(const float* __restrict__ src, unsigned short* __restrict__ dst){
  int i = blockIdx.x*256 + threadIdx.x;
  f32x4 v = *(const f32x4*)(src + (size_t)i*4);
  us4 o;
  #pragma unroll
  for (int r=0;r<4;++r) o[r] = f2b(v[r]);
  *(us4*)(dst + (size_t)i*4) = o;
}

// ---------------- density chain (all f32) ----------------
__global__ void k_gray(const float* __restrict__ xg, float* __restrict__ gray){
  int b = blockIdx.y, n = blockIdx.x*256 + threadIdx.x;
  const float* p = xg + (size_t)b*256*4096 + n;
  float s0=0,s1=0,s2=0,s3=0;
  for (int c=0;c<256;c+=4){
    s0 += p[(size_t)c*4096];
    s1 += p[(size_t)(c+1)*4096];
    s2 += p[(size_t)(c+2)*4096];
    s3 += p[(size_t)(c+3)*4096];
  }
  gray[b*4096+n] = (s0+s1+s2+s3)*(1.f/256.f);
}

__global__ void k_lapabs(const float* __restrict__ gray, float* __restrict__ labs){
  int b = blockIdx.y, n = blockIdx.x*256 + threadIdx.x;
  int hh = n>>6, ww = n&63;
  const float* g = gray + b*4096;
  float c = g[n];
  float up = hh>0  ? g[n-64] : 0.f;
  float dn = hh<63 ? g[n+64] : 0.f;
  float lf = ww>0  ? g[n-1]  : 0.f;
  float rt = ww<63 ? g[n+1]  : 0.f;
  labs[b*4096+n] = fabsf(4.f*c - up - dn - lf - rt);
}

__global__ void k_h8(const float* __restrict__ labs, const float* __restrict__ w1,
                     const float* __restrict__ b1, float* __restrict__ hbuf){
  int b = blockIdx.y, n = blockIdx.x*256 + threadIdx.x;
  int hh = n>>6, ww = n&63;
  const float* L = labs + b*4096;
  float tap[9];
  #pragma unroll
  for (int dy=-1;dy<=1;++dy)
    #pragma unroll
    for (int dx=-1;dx<=1;++dx){
      int y=hh+dy, x2=ww+dx;
      tap[(dy+1)*3+dx+1] = (y>=0&&y<64&&x2>=0&&x2<64)? L[y*64+x2] : 0.f;
    }
  #pragma unroll
  for (int j=0;j<8;++j){
    float a = b1[j];
    #pragma unroll
    for (int k=0;k<9;++k) a += w1[j*9+k]*tap[k];
    hbuf[((size_t)(b*8+j))*4096 + n] = fmaxf(a, 0.f);
  }
}

__global__ void k_scale(const float* __restrict__ hbuf, const float* __restrict__ w2,
                        const float* __restrict__ b2_, float* __restrict__ sc){
  int b = blockIdx.y, n = blockIdx.x*256 + threadIdx.x;
  int hh = n>>6, ww = n&63;
  float a = b2_[0];
  #pragma unroll
  for (int j=0;j<8;++j){
    const float* H = hbuf + ((size_t)(b*8+j))*4096;
    #pragma unroll
    for (int dy=-1;dy<=1;++dy)
      #pragma unroll
      for (int dx=-1;dx<=1;++dx){
        int y=hh+dy, x2=ww+dx;
        if (y>=0&&y<64&&x2>=0&&x2<64) a += w2[j*9+(dy+1)*3+(dx+1)]*H[y*64+x2];
      }
  }
  float sig = 1.f/(1.f+__expf(-a));
  sc[b*4096+n] = 0.0625f/(3.f - 2.f*sig);   // C^-0.5 / (1 + 2*(1-sig))
}

// ---------------- transpose+cast x[b][c][n] (f32) -> Xt[b][n][c] (bf16) ----------------
__global__ void k_transpose(const float* __restrict__ xg, unsigned short* __restrict__ Xtg){
  __shared__ unsigned short T[64*68];
  const int nb = blockIdx.x, cb = blockIdx.y, b = blockIdx.z;
  const int n0 = nb*64, c0 = cb*64;
  const int t = threadIdx.x;
  #pragma unroll
  for (int i=0;i<4;++i){
    int idx = i*256 + t;
    int c = idx>>4, k4 = idx&15;
    f32x4 v = *(const f32x4*)(xg + ((size_t)(b*256 + c0 + c))*4096 + n0 + k4*4);
    us4 o;
    #pragma unroll
    for (int r=0;r<4;++r) o[r] = f2b(v[r]);
    *(us4*)&T[c*68 + k4*4] = o;
  }
  __syncthreads();
  #pragma unroll
  for (int i=0;i<2;++i){
    int idx = i*256 + t;
    int n = idx>>3, ck = idx&7;
    unsigned short vv[8];
    #pragma unroll
    for (int j=0;j<8;++j) vv[j] = T[(ck*8+j)*68 + n];
    *(u32x4*)(Xtg + ((size_t)(b*4096 + n0 + n))*256 + c0 + ck*8) = *(const u32x4*)vv;
  }
}

// ---------------- QKV GEMM: D[o][n] = qkv_w[o][c] * Xt[n][c]^T ----------------
__global__ __launch_bounds__(256,2) void k_gemm_qkv(const unsigned short* __restrict__ Wg,
    const unsigned short* __restrict__ Xtg, const float* __restrict__ biasg,
    unsigned short* __restrict__ Qo, unsigned short* __restrict__ Ko, unsigned short* __restrict__ Vto){
  __shared__ unsigned short Wl[64*256], Xl[64*256];
  const int nt_ = blockIdx.x, at = blockIdx.y, b = blockIdx.z;
  const int a0 = at*64, n0 = nt_*64;
  stage_64x256(Wl, Wg + (size_t)a0*256, 256);
  stage_64x256(Xl, Xtg + ((size_t)(b*4096 + n0))*256, 256);
  __syncthreads();
  const int t = threadIdx.x, w = t>>6, lane = t&63, lam = lane&15, lg = lane>>4;
  f32x4 zz = {0.f,0.f,0.f,0.f};
  f32x4 acc[4] = {zz,zz,zz,zz};
  #pragma unroll
  for (int u=0;u<8;++u){
    int ar = 16*w + lam;
    s16x8 af = *(const s16x8*)((const char*)Wl + ar*512 + ((64*u+16*lg) ^ ((ar&7)<<4)));
    #pragma unroll
    for (int ct=0;ct<4;++ct){
      int br = 16*ct + lam;
      s16x8 bf = *(const s16x8*)((const char*)Xl + br*512 + ((64*u+16*lg) ^ ((br&7)<<4)));
      acc[ct] = MFMA16(af, bf, acc[ct]);
    }
  }
  const int ob = a0 + 16*w + 4*lg;
  f32x4 bias4 = *(const f32x4*)(biasg + ob);
  #pragma unroll
  for (int ct=0;ct<4;++ct){
    int n = n0 + 16*ct + lam;
    us4 ov;
    #pragma unroll
    for (int r=0;r<4;++r) ov[r] = f2b(acc[ct][r] + bias4[r]);
    if (a0 < 256){
      *(us4*)(Qo + ((size_t)(b*4096 + n))*256 + ob) = ov;        // Q[n][c]
    } else if (a0 < 512){
      *(us4*)(Ko + ((size_t)(b*4096 + n))*256 + (ob-256)) = ov;  // K[m][c]
    } else {
      #pragma unroll
      for (int r=0;r<4;++r)
        Vto[((size_t)(b*256 + (ob-512+r)))*4096 + n] = ov[r];    // Vt[c][m]
    }
  }
}

// ---------------- flash attention, 32 q-rows/wave, kv-split 2 ----------------
__global__ __launch_bounds__(256,2) void k_attn(const unsigned short* __restrict__ Qg,
    const unsigned short* __restrict__ Kg, const unsigned short* __restrict__ Vtg,
    const float* __restrict__ Sg, unsigned short* __restrict__ Opg, float* __restrict__ mlg){
  __shared__ unsigned short Kl[64*256];                 // 32KB
  __shared__ unsigned short Vl[256*64];                 // 32KB
  __shared__ __align__(16) unsigned short Pl[4][32*64]; // 16KB (XOR-swizzled per row)

  const int t = threadIdx.x, w = t>>6, lane = t&63, lam = lane&15, lg = lane>>4;
  const int bid = blockIdx.x;
  const int b = bid>>6, qt = (bid>>1)&31, s = bid&1;
  const int qbase = qt*128 + w*32;

  s16x8 qf0[8], qf1[8];
  {
    const unsigned short* qp0 = Qg + ((size_t)(b*4096 + qbase + lam))*256 + lg*8;
    const unsigned short* qp1 = qp0 + 16*256;
    #pragma unroll
    for (int u=0;u<8;++u){ qf0[u] = *(const s16x8*)(qp0 + 32*u); qf1[u] = *(const s16x8*)(qp1 + 32*u); }
  }
  f32x4 zz = {0.f,0.f,0.f,0.f};
  f32x4 oa0[16], oa1[16];
  #pragma unroll
  for (int i=0;i<16;++i){ oa0[i] = zz; oa1[i] = zz; }
  float m_run0 = -1.0e30f, l_run0 = 0.f, m_run1 = -1.0e30f, l_run1 = 0.f;

  for (int kt=0; kt<32; ++kt){
    const int m0 = (s*32 + kt)*64;
    if (kt) __syncthreads();
    stage_64x256(Kl, Kg + ((size_t)(b*4096 + m0))*256, 256);
    stage_256x64(Vl, Vtg + (size_t)b*256*4096 + m0);
    __syncthreads();

    // S^T = K * Q^T for both q-sets; one K-frag read feeds 2 MFMA
    f32x4 st0[4] = {zz,zz,zz,zz}, st1[4] = {zz,zz,zz,zz};
    #pragma unroll
    for (int u=0;u<8;++u){
      #pragma unroll
      for (int mt=0;mt<4;++mt){
        int krow = 16*mt + lam;
        s16x8 kf = *(const s16x8*)((const char*)Kl + krow*512 + ((64*u + 16*lg) ^ ((krow&7)<<4)));
        st0[mt] = MFMA16(kf, qf0[u], st0[mt]);
        st1[mt] = MFMA16(kf, qf1[u], st1[mt]);
      }
    }
    // ---- softmax set 0 ----
    {
      float tmax = -1.0e30f;
      #pragma unroll
      for (int mt=0;mt<4;++mt){
        f32x4 s4 = *(const f32x4*)(Sg + (size_t)b*4096 + m0 + 16*mt + 4*lg);
        #pragma unroll
        for (int r=0;r<4;++r){ st0[mt][r] *= s4[r]; tmax = fmaxf(tmax, st0[mt][r]); }
      }
      tmax = fmaxf(tmax, __shfl_xor(tmax,16));
      tmax = fmaxf(tmax, __shfl_xor(tmax,32));
      float mnew = fmaxf(m_run0, tmax);
      float fs = __expf(m_run0 - mnew);
      float rsum = 0.f;
      #pragma unroll
      for (int mt=0;mt<4;++mt){
        #pragma unroll
        for (int r=0;r<4;++r){ float e = __expf(st0[mt][r]-mnew); st0[mt][r]=e; rsum += e; }
      }
      rsum += __shfl_xor(rsum,16);
      rsum += __shfl_xor(rsum,32);
      l_run0 = l_run0*fs + rsum; m_run0 = mnew;
      const int row = lam;
      #pragma unroll
      for (int mt=0;mt<4;++mt){
        us4 pk;
        #pragma unroll
        for (int r=0;r<4;++r) pk[r] = f2b(st0[mt][r]);
        *(us4*)((char*)&Pl[w][0] + row*128 + ((mt*32 + lg*8) ^ ((row&7)<<4))) = pk;
      }
      float fr[4];
      #pragma unroll
      for (int r=0;r<4;++r) fr[r] = __shfl(fs, 4*lg + r);
      #pragma unroll
      for (int i=0;i<16;++i){
        #pragma unroll
        for (int r=0;r<4;++r) oa0[i][r] *= fr[r];
      }
    }
    // ---- softmax set 1 ----
    {
      float tmax = -1.0e30f;
      #pragma unroll
      for (int mt=0;mt<4;++mt){
        f32x4 s4 = *(const f32x4*)(Sg + (size_t)b*4096 + m0 + 16*mt + 4*lg);
        #pragma unroll
        for (int r=0;r<4;++r){ st1[mt][r] *= s4[r]; tmax = fmaxf(tmax, st1[mt][r]); }
      }
      tmax = fmaxf(tmax, __shfl_xor(tmax,16));
      tmax = fmaxf(tmax, __shfl_xor(tmax,32));
      float mnew = fmaxf(m_run1, tmax);
      float fs = __expf(m_run1 - mnew);
      float rsum = 0.f;
      #pragma unroll
      for (int mt=0;mt<4;++mt){
        #pragma unroll
        for (int r=0;r<4;++r){ float e = __expf(st1[mt][r]-mnew); st1[mt][r]=e; rsum += e; }
      }
      rsum += __shfl_xor(rsum,16);
      rsum += __shfl_xor(rsum,32);
      l_run1 = l_run1*fs + rsum; m_run1 = mnew;
      const int row = 16 + lam;
      #pragma unroll
      for (int mt=0;mt<4;++mt){
        us4 pk;
        #pragma unroll
        for (int r=0;r<4;++r) pk[r] = f2b(st1[mt][r]);
        *(us4*)((char*)&Pl[w][0] + row*128 + ((mt*32 + lg*8) ^ ((row&7)<<4))) = pk;
      }
      float fr[4];
      #pragma unroll
      for (int r=0;r<4;++r) fr[r] = __shfl(fs, 4*lg + r);
      #pragma unroll
      for (int i=0;i<16;++i){
        #pragma unroll
        for (int r=0;r<4;++r) oa1[i][r] *= fr[r];
      }
    }
    // ---- PV: one V-frag read feeds 2 MFMA ----
    #pragma unroll
    for (int ks=0;ks<2;++ks){
      const int r0 = lam, r1 = 16 + lam;
      s16x8 pa0 = *(const s16x8*)((const char*)&Pl[w][0] + r0*128 + ((ks*64 + lg*16) ^ ((r0&7)<<4)));
      s16x8 pa1 = *(const s16x8*)((const char*)&Pl[w][0] + r1*128 + ((ks*64 + lg*16) ^ ((r1&7)<<4)));
      #pragma unroll
      for (int ct=0;ct<16;++ct){
        int c = lam + 16*ct;
        s16x8 vf = *(const s16x8*)((const char*)Vl + c*128 + ((ks*64 + 16*lg) ^ ((c&7)<<4)));
        oa0[ct] = MFMA16(pa0, vf, oa0[ct]);
        oa1[ct] = MFMA16(pa1, vf, oa1[ct]);
      }
    }
  }
  // epilogue: per-split normalized O + (m,l)
  const size_t obase = ((size_t)(b*2 + s))*4096;
  {
    float li = 1.f/l_run0;
    float lr[4];
    #pragma unroll
    for (int r=0;r<4;++r) lr[r] = __shfl(li, 4*lg + r);
    #pragma unroll
    for (int ct=0;ct<16;++ct){
      #pragma unroll
      for (int r=0;r<4;++r)
        Opg[(obase + qbase + 4*lg + r)*256 + lam + 16*ct] = f2b(oa0[ct][r]*lr[r]);
    }
    if (lane < 16){
      mlg[(obase + qbase + lam)*2]     = m_run0;
      mlg[(obase + qbase + lam)*2 + 1] = l_run0;
    }
  }
  {
    float li = 1.f/l_run1;
    float lr[4];
    #pragma unroll
    for (int r=0;r<4;++r) lr[r] = __shfl(li, 4*lg + r);
    #pragma unroll
    for (int ct=0;ct<16;++ct){
      #pragma unroll
      for (int r=0;r<4;++r)
        Opg[(obase + qbase + 16 + 4*lg + r)*256 + lam + 16*ct] = f2b(oa1[ct][r]*lr[r]);
    }
    if (lane < 16){
      mlg[(obase + qbase + 16 + lam)*2]     = m_run1;
      mlg[(obase + qbase + 16 + lam)*2 + 1] = l_run1;
    }
  }
}

// ---------------- merge the 2 kv-splits ----------------
__global__ void k_merge(const unsigned short* __restrict__ Opg, const float* __restrict__ mlg,
                        unsigned short* __restrict__ AOt){
  int rr = blockIdx.x*8 + (threadIdx.x>>5);
  int b = rr>>12, n = rr&4095;
  int c0 = (threadIdx.x&31)*8;
  size_t base0 = ((size_t)(b*2+0))*4096 + n;
  size_t base1 = ((size_t)(b*2+1))*4096 + n;
  float m0 = mlg[base0*2], l0 = mlg[base0*2+1];
  float m1 = mlg[base1*2], l1 = mlg[base1*2+1];
  float M = fmaxf(m0,m1);
  float w0 = __expf(m0-M)*l0, w1 = __expf(m1-M)*l1;
  float inv = 1.f/(w0+w1);
  w0 *= inv; w1 *= inv;
  u32x4 a = *(const u32x4*)(Opg + base0*256 + c0);
  u32x4 c = *(const u32x4*)(Opg + base1*256 + c0);
  u32x4 o;
  #pragma unroll
  for (int k=0;k<4;++k){
    float alo = b2f((unsigned short)(a[k]&0xffffu)), ahi = b2f((unsigned short)(a[k]>>16));
    float clo = b2f((unsigned short)(c[k]&0xffffu)), chi = b2f((unsigned short)(c[k]>>16));
    unsigned lo = f2b(w0*alo + w1*clo);
    unsigned hi = f2b(w0*ahi + w1*chi);
    o[k] = lo | (hi<<16);
  }
  *(u32x4*)(AOt + ((size_t)(b*4096+n))*256 + c0) = o;
}

// ---------------- OUT GEMM: out[o][n] = AOt[n][c]*out_w[o][c]^T + bias + x (f32 out) ----------------
__global__ __launch_bounds__(256,2) void k_gemm_out(const unsigned short* __restrict__ Ag,
    const unsigned short* __restrict__ Bg, const float* __restrict__ biasg,
    const float* __restrict__ xg, float* __restrict__ outg){
  __shared__ unsigned short Al[64*256], Bl[64*256];
  const int at = blockIdx.x, bt = blockIdx.y, b = blockIdx.z;
  const int a0 = at*64, o0 = bt*64;
  stage_64x256(Al, Ag + ((size_t)(b*4096 + a0))*256, 256);
  stage_64x256(Bl, Bg + (size_t)o0*256, 256);
  __syncthreads();
  const int t = threadIdx.x, w = t>>6, lane = t&63, lam = lane&15, lg = lane>>4;
  f32x4 zz = {0.f,0.f,0.f,0.f};
  f32x4 acc[4] = {zz,zz,zz,zz};
  #pragma unroll
  for (int u=0;u<8;++u){
    int ar = 16*w + lam;
    s16x8 af = *(const s16x8*)((const char*)Al + ar*512 + ((64*u+16*lg) ^ ((ar&7)<<4)));
    #pragma unroll
    for (int ct=0;ct<4;++ct){
      int br = 16*ct + lam;
      s16x8 bf = *(const s16x8*)((const char*)Bl + br*512 + ((64*u+16*lg) ^ ((br&7)<<4)));
      acc[ct] = MFMA16(af, bf, acc[ct]);
    }
  }
  #pragma unroll
  for (int ct=0;ct<4;++ct){
    int o = o0 + 16*ct + lam;
    float ob_ = biasg[o];
    size_t base = ((size_t)(b*256 + o))*4096 + a0 + 16*w + 4*lg;
    f32x4 xv = *(const f32x4*)(xg + base);
    f32x4 ov;
    #pragma unroll
    for (int r=0;r<4;++r) ov[r] = acc[ct][r] + ob_ + xv[r];
    *(f32x4*)(outg + base) = ov;
  }
}

extern "C" void kernel_launch(void* const* d_in, const int* in_sizes, int n_in,
                              void* d_out, int out_size, void* d_ws, size_t ws_size,
                              hipStream_t stream){
  const float* x     = (const float*)d_in[0];
  const float* qkv_w = (const float*)d_in[1];
  const float* qkv_b = (const float*)d_in[2];
  const float* out_w = (const float*)d_in[3];
  const float* out_b = (const float*)d_in[4];
  const float* d1_w  = (const float*)d_in[5];
  const float* d1_b  = (const float*)d_in[6];
  const float* d2_w  = (const float*)d_in[7];
  const float* d2_b  = (const float*)d_in[8];
  float* out = (float*)d_out;

  char* p = (char*)d_ws;
  const size_t BIG = (size_t)8*4096*256*2;
  unsigned short* Xt = (unsigned short*)p; p += BIG;   // reused as AOt after QKV GEMM
  unsigned short* Q  = (unsigned short*)p; p += BIG;
  unsigned short* K  = (unsigned short*)p; p += BIG;
  unsigned short* Vt = (unsigned short*)p; p += BIG;
  unsigned short* Wq = (unsigned short*)p; p += (size_t)768*256*2;
  unsigned short* Wo = (unsigned short*)p; p += (size_t)256*256*2;
  float* gray = (float*)p; p += (size_t)8*4096*4;
  float* labs = (float*)p; p += (size_t)8*4096*4;
  float* hbuf = (float*)p; p += (size_t)8*8*4096*4;
  float* sc   = (float*)p; p += (size_t)8*4096*4;
  unsigned short* Op = (unsigned short*)p; p += (size_t)8*2*4096*256*2;
  float* ml = (float*)p; p += (size_t)8*2*4096*2*4;

  k_cvt      <<<dim3(192),    256, 0, stream>>>(qkv_w, Wq);
  k_cvt      <<<dim3(64),     256, 0, stream>>>(out_w, Wo);
  k_transpose<<<dim3(64,4,8), 256, 0, stream>>>(x, Xt);
  k_gray     <<<dim3(16,8),   256, 0, stream>>>(x, gray);
  k_lapabs   <<<dim3(16,8),   256, 0, stream>>>(gray, labs);
  k_h8       <<<dim3(16,8),   256, 0, stream>>>(labs, d1_w, d1_b, hbuf);
  k_scale    <<<dim3(16,8),   256, 0, stream>>>(hbuf, d2_w, d2_b, sc);
  k_gemm_qkv <<<dim3(64,12,8),256, 0, stream>>>(Wq, Xt, qkv_b, Q, K, Vt);
  k_attn     <<<dim3(512),    256, 0, stream>>>(Q, K, Vt, sc, Op, ml);
  k_merge    <<<dim3(4096),   256, 0, stream>>>(Op, ml, Xt);
  k_gemm_out <<<dim3(64,4,8), 256, 0, stream>>>(Xt, Wo, out_b, x, out);
}

// Round 4
// 325.824 us; speedup vs baseline: 1.2577x; 1.2577x over previous
//
#include <hip/hip_runtime.h>
#include <hip/hip_bf16.h>

typedef __attribute__((ext_vector_type(8))) short s16x8;
typedef __attribute__((ext_vector_type(4))) float f32x4;
typedef __attribute__((ext_vector_type(4))) unsigned short us4;
typedef __attribute__((ext_vector_type(4))) unsigned int u32x4;

#define MFMA16(a,b,c) __builtin_amdgcn_mfma_f32_16x16x32_bf16((a),(b),(c),0,0,0)

__device__ __forceinline__ float b2f(unsigned short u){
  union{unsigned u; float f;} v; v.u = ((unsigned)u)<<16; return v.f;
}
__device__ __forceinline__ unsigned short f2b(float f){
  union{float f; unsigned u;} v; v.f = f;
  unsigned r = v.u + 0x7fffu + ((v.u>>16)&1u);
  return (unsigned short)(r>>16);
}

__device__ __forceinline__ void gl_lds16(const void* gp, void* lp){
  __builtin_amdgcn_global_load_lds((const __attribute__((address_space(1))) void*)gp,
                                   (__attribute__((address_space(3))) void*)lp, 16, 0, 0);
}

// ---- 256-thread staging helpers (GEMM kernels) ----
__device__ __forceinline__ void stage_64x256(void* lds, const unsigned short* g, int stride){
  const int t = threadIdx.x, wv = t>>6;
  #pragma unroll
  for (int i=0;i<8;++i){
    int ch = i*256 + t;
    int row = ch>>5, cc = ch&31, sc = cc ^ (row&7);
    gl_lds16((const char*)(g + (size_t)row*stride) + sc*16,
             (char*)lds + (((size_t)i*256 + wv*64)<<4));
  }
}
// ---- 512-thread staging helpers (attention) ----
__device__ __forceinline__ void stage_K512(void* lds, const unsigned short* g){
  const int t = threadIdx.x, wv = t>>6;
  #pragma unroll
  for (int i=0;i<4;++i){
    int ch = i*512 + t;
    int row = ch>>5, cc = ch&31, sc = cc ^ (row&7);
    gl_lds16((const char*)g + (size_t)row*512 + sc*16,
             (char*)lds + (((size_t)i*512 + wv*64)<<4));
  }
}
__device__ __forceinline__ void stage_V512(void* lds, const unsigned short* g){
  const int t = threadIdx.x, wv = t>>6;
  #pragma unroll
  for (int i=0;i<4;++i){
    int ch = i*512 + t;
    int row = ch>>3, cc = ch&7, sc = cc ^ (row&7);
    gl_lds16((const char*)(g + (size_t)row*4096) + sc*16,
             (char*)lds + (((size_t)i*512 + wv*64)<<4));
  }
}

// ---------------- f32 -> bf16 cast ----------------
__global__ void k_cvt(const float* __restrict__ src, unsigned short* __restrict__ dst){
  int i = blockIdx.x*256 + threadIdx.x;
  f32x4 v = *(const f32x4*)(src + (size_t)i*4);
  us4 o;
  #pragma unroll
  for (int r=0;r<4;++r) o[r] = f2b(v[r]);
  *(us4*)(dst + (size_t)i*4) = o;
}

// ---------------- density chain (all f32) ----------------
__global__ void k_gray(const float* __restrict__ xg, float* __restrict__ gray){
  int b = blockIdx.y, n = blockIdx.x*256 + threadIdx.x;
  const float* p = xg + (size_t)b*256*4096 + n;
  float s0=0,s1=0,s2=0,s3=0;
  for (int c=0;c<256;c+=4){
    s0 += p[(size_t)c*4096];
    s1 += p[(size_t)(c+1)*4096];
    s2 += p[(size_t)(c+2)*4096];
    s3 += p[(size_t)(c+3)*4096];
  }
  gray[b*4096+n] = (s0+s1+s2+s3)*(1.f/256.f);
}

__global__ void k_lapabs(const float* __restrict__ gray, float* __restrict__ labs){
  int b = blockIdx.y, n = blockIdx.x*256 + threadIdx.x;
  int hh = n>>6, ww = n&63;
  const float* g = gray + b*4096;
  float c = g[n];
  float up = hh>0  ? g[n-64] : 0.f;
  float dn = hh<63 ? g[n+64] : 0.f;
  float lf = ww>0  ? g[n-1]  : 0.f;
  float rt = ww<63 ? g[n+1]  : 0.f;
  labs[b*4096+n] = fabsf(4.f*c - up - dn - lf - rt);
}

__global__ void k_h8(const float* __restrict__ labs, const float* __restrict__ w1,
                     const float* __restrict__ b1, float* __restrict__ hbuf){
  int b = blockIdx.y, n = blockIdx.x*256 + threadIdx.x;
  int hh = n>>6, ww = n&63;
  const float* L = labs + b*4096;
  float tap[9];
  #pragma unroll
  for (int dy=-1;dy<=1;++dy)
    #pragma unroll
    for (int dx=-1;dx<=1;++dx){
      int y=hh+dy, x2=ww+dx;
      tap[(dy+1)*3+dx+1] = (y>=0&&y<64&&x2>=0&&x2<64)? L[y*64+x2] : 0.f;
    }
  #pragma unroll
  for (int j=0;j<8;++j){
    float a = b1[j];
    #pragma unroll
    for (int k=0;k<9;++k) a += w1[j*9+k]*tap[k];
    hbuf[((size_t)(b*8+j))*4096 + n] = fmaxf(a, 0.f);
  }
}

__global__ void k_scale(const float* __restrict__ hbuf, const float* __restrict__ w2,
                        const float* __restrict__ b2_, float* __restrict__ sc){
  int b = blockIdx.y, n = blockIdx.x*256 + threadIdx.x;
  int hh = n>>6, ww = n&63;
  float a = b2_[0];
  #pragma unroll
  for (int j=0;j<8;++j){
    const float* H = hbuf + ((size_t)(b*8+j))*4096;
    #pragma unroll
    for (int dy=-1;dy<=1;++dy)
      #pragma unroll
      for (int dx=-1;dx<=1;++dx){
        int y=hh+dy, x2=ww+dx;
        if (y>=0&&y<64&&x2>=0&&x2<64) a += w2[j*9+(dy+1)*3+(dx+1)]*H[y*64+x2];
      }
  }
  float sig = 1.f/(1.f+__expf(-a));
  sc[b*4096+n] = 0.0625f/(3.f - 2.f*sig);   // C^-0.5 / (1 + 2*(1-sig))
}

// ---------------- transpose+cast x[b][c][n] (f32) -> Xt[b][n][c] (bf16) ----------------
__global__ void k_transpose(const float* __restrict__ xg, unsigned short* __restrict__ Xtg){
  __shared__ unsigned short T[64*68];
  const int nb = blockIdx.x, cb = blockIdx.y, b = blockIdx.z;
  const int n0 = nb*64, c0 = cb*64;
  const int t = threadIdx.x;
  #pragma unroll
  for (int i=0;i<4;++i){
    int idx = i*256 + t;
    int c = idx>>4, k4 = idx&15;
    f32x4 v = *(const f32x4*)(xg + ((size_t)(b*256 + c0 + c))*4096 + n0 + k4*4);
    us4 o;
    #pragma unroll
    for (int r=0;r<4;++r) o[r] = f2b(v[r]);
    *(us4*)&T[c*68 + k4*4] = o;
  }
  __syncthreads();
  #pragma unroll
  for (int i=0;i<2;++i){
    int idx = i*256 + t;
    int n = idx>>3, ck = idx&7;
    unsigned short vv[8];
    #pragma unroll
    for (int j=0;j<8;++j) vv[j] = T[(ck*8+j)*68 + n];
    *(u32x4*)(Xtg + ((size_t)(b*4096 + n0 + n))*256 + c0 + ck*8) = *(const u32x4*)vv;
  }
}

// ---------------- QKV GEMM: D[o][n] = qkv_w[o][c] * Xt[n][c]^T ----------------
__global__ __launch_bounds__(256,2) void k_gemm_qkv(const unsigned short* __restrict__ Wg,
    const unsigned short* __restrict__ Xtg, const float* __restrict__ biasg,
    unsigned short* __restrict__ Qo, unsigned short* __restrict__ Ko, unsigned short* __restrict__ Vto){
  __shared__ unsigned short Wl[64*256], Xl[64*256];
  const int nt_ = blockIdx.x, at = blockIdx.y, b = blockIdx.z;
  const int a0 = at*64, n0 = nt_*64;
  stage_64x256(Wl, Wg + (size_t)a0*256, 256);
  stage_64x256(Xl, Xtg + ((size_t)(b*4096 + n0))*256, 256);
  __syncthreads();
  const int t = threadIdx.x, w = t>>6, lane = t&63, lam = lane&15, lg = lane>>4;
  f32x4 zz = {0.f,0.f,0.f,0.f};
  f32x4 acc[4] = {zz,zz,zz,zz};
  #pragma unroll
  for (int u=0;u<8;++u){
    int ar = 16*w + lam;
    s16x8 af = *(const s16x8*)((const char*)Wl + ar*512 + ((64*u+16*lg) ^ ((ar&7)<<4)));
    #pragma unroll
    for (int ct=0;ct<4;++ct){
      int br = 16*ct + lam;
      s16x8 bf = *(const s16x8*)((const char*)Xl + br*512 + ((64*u+16*lg) ^ ((br&7)<<4)));
      acc[ct] = MFMA16(af, bf, acc[ct]);
    }
  }
  const int ob = a0 + 16*w + 4*lg;
  f32x4 bias4 = *(const f32x4*)(biasg + ob);
  #pragma unroll
  for (int ct=0;ct<4;++ct){
    int n = n0 + 16*ct + lam;
    us4 ov;
    #pragma unroll
    for (int r=0;r<4;++r) ov[r] = f2b(acc[ct][r] + bias4[r]);
    if (a0 < 256){
      *(us4*)(Qo + ((size_t)(b*4096 + n))*256 + ob) = ov;        // Q[n][c]
    } else if (a0 < 512){
      *(us4*)(Ko + ((size_t)(b*4096 + n))*256 + (ob-256)) = ov;  // K[m][c]
    } else {
      #pragma unroll
      for (int r=0;r<4;++r)
        Vto[((size_t)(b*256 + (ob-512+r)))*4096 + n] = ov[r];    // Vt[c][m]
    }
  }
}

// ---------------- flash attention: 8 waves/block, dbuf K/V, 1 barrier/tile ----------------
__global__ __launch_bounds__(512,2) void k_attn(const unsigned short* __restrict__ Qg,
    const unsigned short* __restrict__ Kg, const unsigned short* __restrict__ Vtg,
    const float* __restrict__ Sg, unsigned short* __restrict__ AOt){
  __shared__ unsigned short Kl[2][64*256];               // 2 x 32KB
  __shared__ unsigned short Vl[2][256*64];               // 2 x 32KB
  __shared__ __align__(16) unsigned short Pl[8][16*64];  // 8 x 2KB, XOR-swizzled rows

  const int t = threadIdx.x, w = t>>6, lane = t&63, lam = lane&15, lg = lane>>4;
  const int bid = blockIdx.x;
  const int b = bid&7, qt = bid>>3;        // XCD-major: batch b pinned to XCD b
  const int qbase = qt*128 + w*16;

  s16x8 qf[8];
  {
    const unsigned short* qp = Qg + ((size_t)(b*4096 + qbase + lam))*256 + lg*8;
    #pragma unroll
    for (int u=0;u<8;++u) qf[u] = *(const s16x8*)(qp + 32*u);
  }
  f32x4 zz = {0.f,0.f,0.f,0.f};
  f32x4 oa[16];
  #pragma unroll
  for (int i=0;i<16;++i) oa[i] = zz;
  float m_run = -1.0e30f, l_run = 0.f;

  const unsigned short* Kb = Kg + (size_t)b*4096*256;
  const unsigned short* Vb = Vtg + (size_t)b*256*4096;

  // prologue: stage tile 0 into buffer 0
  stage_K512(&Kl[0][0], Kb);
  stage_V512(&Vl[0][0], Vb);
  __syncthreads();

  int cur = 0;
  for (int kt=0; kt<64; ++kt){
    const int m0 = kt*64;
    // async stage of tile kt+1 into the other buffer (hidden under compute)
    if (kt < 63){
      stage_K512(&Kl[cur^1][0], Kb + (size_t)(m0+64)*256);
      stage_V512(&Vl[cur^1][0], Vb + (m0+64));
    }
    // prefetch per-key scales (overlaps QK MFMAs)
    f32x4 s4[4];
    #pragma unroll
    for (int mt=0;mt<4;++mt) s4[mt] = *(const f32x4*)(Sg + (size_t)b*4096 + m0 + 16*mt + 4*lg);

    // S^T = K * Q^T  -> lane owns q-row lam, keys {16mt+4lg+r}
    f32x4 st[4] = {zz,zz,zz,zz};
    const char* Kc = (const char*)&Kl[cur][0];
    __builtin_amdgcn_s_setprio(1);
    #pragma unroll
    for (int u=0;u<8;++u){
      #pragma unroll
      for (int mt=0;mt<4;++mt){
        int krow = 16*mt + lam;
        s16x8 kf = *(const s16x8*)(Kc + krow*512 + ((64*u + 16*lg) ^ ((krow&7)<<4)));
        st[mt] = MFMA16(kf, qf[u], st[mt]);
      }
    }
    __builtin_amdgcn_s_setprio(0);

    // per-key temperature scale + online softmax
    float tmax = -1.0e30f;
    #pragma unroll
    for (int mt=0;mt<4;++mt){
      #pragma unroll
      for (int r=0;r<4;++r){ st[mt][r] *= s4[mt][r]; tmax = fmaxf(tmax, st[mt][r]); }
    }
    tmax = fmaxf(tmax, __shfl_xor(tmax,16));
    tmax = fmaxf(tmax, __shfl_xor(tmax,32));
    float mnew = fmaxf(m_run, tmax);
    float fs = __expf(m_run - mnew);
    float rsum = 0.f;
    #pragma unroll
    for (int mt=0;mt<4;++mt){
      #pragma unroll
      for (int r=0;r<4;++r){ float e = __expf(st[mt][r]-mnew); st[mt][r]=e; rsum += e; }
    }
    rsum += __shfl_xor(rsum,16);
    rsum += __shfl_xor(rsum,32);
    l_run = l_run*fs + rsum; m_run = mnew;

    // P -> per-wave swizzled LDS [16 rows][64 keys]
    #pragma unroll
    for (int mt=0;mt<4;++mt){
      us4 pk;
      #pragma unroll
      for (int r=0;r<4;++r) pk[r] = f2b(st[mt][r]);
      *(us4*)((char*)&Pl[w][0] + lam*128 + ((mt*32 + lg*8) ^ ((lam&7)<<4))) = pk;
    }
    // rescale O accumulator
    float fr[4];
    #pragma unroll
    for (int r=0;r<4;++r) fr[r] = __shfl(fs, 4*lg + r);
    #pragma unroll
    for (int i=0;i<16;++i){
      #pragma unroll
      for (int r=0;r<4;++r) oa[i][r] *= fr[r];
    }
    // PV
    const char* Vc = (const char*)&Vl[cur][0];
    __builtin_amdgcn_s_setprio(1);
    #pragma unroll
    for (int ks=0;ks<2;++ks){
      s16x8 pa = *(const s16x8*)((const char*)&Pl[w][0] + lam*128 + ((ks*64 + lg*16) ^ ((lam&7)<<4)));
      #pragma unroll
      for (int ct=0;ct<16;++ct){
        int c = lam + 16*ct;
        s16x8 vf = *(const s16x8*)(Vc + c*128 + ((ks*64 + 16*lg) ^ ((c&7)<<4)));
        oa[ct] = MFMA16(pa, vf, oa[ct]);
      }
    }
    __builtin_amdgcn_s_setprio(0);

    __syncthreads();   // drains this wave's stage loads (vmcnt) + all waves done reading buf[cur]
    cur ^= 1;
  }
  // epilogue: normalize, write AOt[n][c]
  float li = 1.f/l_run;
  float lr[4];
  #pragma unroll
  for (int r=0;r<4;++r) lr[r] = __shfl(li, 4*lg + r);
  #pragma unroll
  for (int ct=0;ct<16;++ct){
    #pragma unroll
    for (int r=0;r<4;++r){
      AOt[((size_t)(b*4096 + qbase + 4*lg + r))*256 + lam + 16*ct] = f2b(oa[ct][r]*lr[r]);
    }
  }
}

// ---------------- OUT GEMM: out[o][n] = AOt[n][c]*out_w[o][c]^T + bias + x (f32 out) ----------------
__global__ __launch_bounds__(256,2) void k_gemm_out(const unsigned short* __restrict__ Ag,
    const unsigned short* __restrict__ Bg, const float* __restrict__ biasg,
    const float* __restrict__ xg, float* __restrict__ outg){
  __shared__ unsigned short Al[64*256], Bl[64*256];
  const int at = blockIdx.x, bt = blockIdx.y, b = blockIdx.z;
  const int a0 = at*64, o0 = bt*64;
  stage_64x256(Al, Ag + ((size_t)(b*4096 + a0))*256, 256);
  stage_64x256(Bl, Bg + (size_t)o0*256, 256);
  __syncthreads();
  const int t = threadIdx.x, w = t>>6, lane = t&63, lam = lane&15, lg = lane>>4;
  f32x4 zz = {0.f,0.f,0.f,0.f};
  f32x4 acc[4] = {zz,zz,zz,zz};
  #pragma unroll
  for (int u=0;u<8;++u){
    int ar = 16*w + lam;
    s16x8 af = *(const s16x8*)((const char*)Al + ar*512 + ((64*u+16*lg) ^ ((ar&7)<<4)));
    #pragma unroll
    for (int ct=0;ct<4;++ct){
      int br = 16*ct + lam;
      s16x8 bf = *(const s16x8*)((const char*)Bl + br*512 + ((64*u+16*lg) ^ ((br&7)<<4)));
      acc[ct] = MFMA16(af, bf, acc[ct]);
    }
  }
  #pragma unroll
  for (int ct=0;ct<4;++ct){
    int o = o0 + 16*ct + lam;
    float ob_ = biasg[o];
    size_t base = ((size_t)(b*256 + o))*4096 + a0 + 16*w + 4*lg;
    f32x4 xv = *(const f32x4*)(xg + base);
    f32x4 ov;
    #pragma unroll
    for (int r=0;r<4;++r) ov[r] = acc[ct][r] + ob_ + xv[r];
    *(f32x4*)(outg + base) = ov;
  }
}

extern "C" void kernel_launch(void* const* d_in, const int* in_sizes, int n_in,
                              void* d_out, int out_size, void* d_ws, size_t ws_size,
                              hipStream_t stream){
  const float* x     = (const float*)d_in[0];
  const float* qkv_w = (const float*)d_in[1];
  const float* qkv_b = (const float*)d_in[2];
  const float* out_w = (const float*)d_in[3];
  const float* out_b = (const float*)d_in[4];
  const float* d1_w  = (const float*)d_in[5];
  const float* d1_b  = (const float*)d_in[6];
  const float* d2_w  = (const float*)d_in[7];
  const float* d2_b  = (const float*)d_in[8];
  float* out = (float*)d_out;

  char* p = (char*)d_ws;
  const size_t BIG = (size_t)8*4096*256*2;
  unsigned short* Xt = (unsigned short*)p; p += BIG;   // reused as AOt after QKV GEMM
  unsigned short* Q  = (unsigned short*)p; p += BIG;
  unsigned short* K  = (unsigned short*)p; p += BIG;
  unsigned short* Vt = (unsigned short*)p; p += BIG;
  unsigned short* Wq = (unsigned short*)p; p += (size_t)768*256*2;
  unsigned short* Wo = (unsigned short*)p; p += (size_t)256*256*2;
  float* gray = (float*)p; p += (size_t)8*4096*4;
  float* labs = (float*)p; p += (size_t)8*4096*4;
  float* hbuf = (float*)p; p += (size_t)8*8*4096*4;
  float* sc   = (float*)p; p += (size_t)8*4096*4;

  k_cvt      <<<dim3(192),    256, 0, stream>>>(qkv_w, Wq);
  k_cvt      <<<dim3(64),     256, 0, stream>>>(out_w, Wo);
  k_transpose<<<dim3(64,4,8), 256, 0, stream>>>(x, Xt);
  k_gray     <<<dim3(16,8),   256, 0, stream>>>(x, gray);
  k_lapabs   <<<dim3(16,8),   256, 0, stream>>>(gray, labs);
  k_h8       <<<dim3(16,8),   256, 0, stream>>>(labs, d1_w, d1_b, hbuf);
  k_scale    <<<dim3(16,8),   256, 0, stream>>>(hbuf, d2_w, d2_b, sc);
  k_gemm_qkv <<<dim3(64,12,8),256, 0, stream>>>(Wq, Xt, qkv_b, Q, K, Vt);
  k_attn     <<<dim3(256),    512, 0, stream>>>(Q, K, Vt, sc, Xt);
  k_gemm_out <<<dim3(64,4,8), 256, 0, stream>>>(Xt, Wo, out_b, x, out);
}